// Round 9
// baseline (448.422 us; speedup 1.0000x reference)
//
#include <hip/hip_runtime.h>
#include <hip/hip_bf16.h>
#include <math.h>

// ---------------------------------------------------------------------------
// ContMixT: f_concat -> conv3x3(d2) BN ReLU -> conv3x3(d4) BN ReLU -> pool ->
// 1x1 -> fc -> per-(batch,channel) 3x3 depthwise -> two 1x1 gates -> blend.
// conv1/conv2: bf16 MFMA implicit GEMM (m97-style 128x128 tile, BK=64,
// global_load_lds width=16, xor-swizzled LDS) — R2 structure, PROVEN; R3/R6/R8
// falsified dbuf, in-block split-K, and cross-block split-K: ~130us/36%
// MfmaUtil is this structure's ceiling. Do not touch.
// R1: pad_concat tiled transpose. R2: c0-outer/tap-inner + XCD swizzle.
// R4/R5: alpha+final fused, register-resident; gap fused into pad_concat;
// border stores instead of memsets. R6b: dw LDS-tiled. R9: aux consolidation.
// R10: (a) alpha_final float4 loads (24 instead of 96 load-instrs/thread,
//      same bytes) via (x4,8ch-slice) thread map; (b) pad_concat+aux merged
//      into one prep_kernel (gpool/gapv zero back to memset — must precede
//      pad's gapv atomics); (c) fcG folded into fc1 (per-block G recompute,
//      ~1us redundant MAC, one less dependent launch).
// ---------------------------------------------------------------------------

typedef __bf16 bf16x8 __attribute__((ext_vector_type(8)));
typedef float f32x4 __attribute__((ext_vector_type(4)));
typedef __attribute__((address_space(1))) void as1_void;
typedef __attribute__((address_space(3))) void as3_void;

__device__ __forceinline__ void f4acc(float4& a, float s, const float4& v) {
  a.x += s * v.x; a.y += s * v.y; a.z += s * v.z; a.w += s * v.w;
}
__device__ __forceinline__ float blend1(float al, float ap, float a, float b, float c) {
  return al * a + (1.f - al) * (ap * b + (1.f - ap) * c);
}

// ---------------- prep: pad_concat + repack + borders + BN fold ----------
// grid 5441: [0,2304) pad_concat; [2304,4352) weight repack;
// [4352,5440) h1p border zero; [5440] BN fold.
__global__ __launch_bounds__(256) void prep_kernel(
    const float* __restrict__ f2, const float* __restrict__ f1, const float* __restrict__ f0,
    __hip_bfloat16* __restrict__ out, float* __restrict__ gapv,
    const float* __restrict__ w1, const float* __restrict__ w2,
    const float* __restrict__ ob1, const float* __restrict__ g1, const float* __restrict__ b1,
    const float* __restrict__ m1, const float* __restrict__ v1,
    const float* __restrict__ ob2, const float* __restrict__ g2, const float* __restrict__ b2,
    const float* __restrict__ m2, const float* __restrict__ v2,
    __hip_bfloat16* __restrict__ wt1, __hip_bfloat16* __restrict__ wt2,
    __hip_bfloat16* __restrict__ h1p, float* __restrict__ cst)
{
  __shared__ float shbuf[128 * 85];
  const uint4 z4 = {0u, 0u, 0u, 0u};

  if (blockIdx.x < 2304) {
    // ---- pad_concat: NCHW fp32 x3 -> padded NHWC bf16, + gap row-sums ----
    int bid = blockIdx.x;
    const int cg = bid % 6; bid /= 6;
    const int y = bid % 48;
    const int b = bid / 48;
    const float* src = (cg < 2) ? f2 : ((cg < 4) ? f1 : f0);
    const int ccbase = (cg & 1) * 128;

    // phase 1: 128 c x 20 x4 = 2560 float4 loads, 10 per thread
#pragma unroll
    for (int it = 0; it < 10; it++) {
      const int idx = it * 256 + threadIdx.x;
      const int cl = idx / 20, x4 = idx % 20;
      const float4 v = *(const float4*)(src +
          (((size_t)b * 256 + ccbase + cl) * 48 + y) * 80 + x4 * 4);
      float* t = shbuf + cl * 85 + x4 * 4;
      t[0] = v.x; t[1] = v.y; t[2] = v.z; t[3] = v.w;
    }

    // x-borders of this padded row (x = 0,1,82,83), 128 ch = 32 uint4
    if (threadIdx.x < 32) {
      const int xb_ = threadIdx.x >> 3, ch8 = threadIdx.x & 7;
      const int xx = (xb_ < 2) ? xb_ : (80 + xb_);
      *(uint4*)(out + ((size_t)(b * 52 + y + 2) * 84 + xx) * 768 + cg * 128 + ch8 * 8) = z4;
    }
    // y-border rows (0,1 by y==0 blocks; 50,51 by y==47 blocks)
    if (y == 0 || y == 47) {
      const int r0 = (y == 0) ? 0 : 50;
      for (int idx = threadIdx.x; idx < 1344; idx += 256) {
        const int rr = idx / 672, rem = idx % 672;
        const int xx = rem >> 3, ch8 = rem & 7;
        *(uint4*)(out + ((size_t)(b * 52 + r0 + rr) * 84 + xx) * 768 + cg * 128 + ch8 * 8) = z4;
      }
    }
    __syncthreads();

    // phase 2: 80 x x 16 chunks = 1280 16B stores, 5 per thread
    __hip_bfloat16* obase = out + ((size_t)(b * 52 + y + 2) * 84 + 2) * 768 + cg * 128;
#pragma unroll
    for (int it = 0; it < 5; it++) {
      const int idx = it * 256 + threadIdx.x;
      const int chunk = idx & 15, x = idx >> 4;
      const float* t = shbuf + chunk * 8 * 85 + x;
      union { __hip_bfloat16 h[8]; uint4 u; } pk;
#pragma unroll
      for (int j = 0; j < 8; j++) pk.h[j] = __float2bfloat16(t[j * 85]);
      *(uint4*)(obase + (size_t)x * 768 + chunk * 8) = pk.u;
    }

    // gap row-sums for f_t (cg 4,5 -> i=b) and f_tm1 (cg 2,3 -> i=b+8)
    if (cg >= 2) {
      const int i_gap = (cg >= 4) ? b : (b + 8);
      const int cl = threadIdx.x >> 1, half = threadIdx.x & 1;
      const float* t = shbuf + cl * 85 + half * 40;
      float s = 0.f;
#pragma unroll
      for (int k = 0; k < 40; k++) s += t[k];
      s += __shfl_xor(s, 1);
      if (half == 0) atomicAdd(&gapv[i_gap * 256 + ccbase + cl], s);
    }
    return;
  }

  const int abid = blockIdx.x - 2304;
  if (abid < 2048) {
    // ---- coalesced weight repack: OIHW fp32 -> [tap][oc][ic] bf16 ----
    const float* w = (abid < 1536) ? w1 : w2;
    __hip_bfloat16* dst = (abid < 1536) ? wt1 : wt2;
    const int IC = (abid < 1536) ? 768 : 256;
    const int lb = (abid < 1536) ? abid : (abid - 1536);
    const int nicb = IC >> 7;
    const int icb = lb % nicb, oc = lb / nicb;
    const int ic0 = icb * 128;
    const float* src = w + ((size_t)oc * IC + ic0) * 9;
    for (int k = threadIdx.x; k < 1152; k += 256) shbuf[k] = src[k];
    __syncthreads();
    if (threadIdx.x < 144) {
      const int tap = threadIdx.x / 16, ch = threadIdx.x % 16;
      union { __hip_bfloat16 h[8]; uint4 u; } pk;
#pragma unroll
      for (int j = 0; j < 8; j++) pk.h[j] = __float2bfloat16(shbuf[(ch * 8 + j) * 9 + tap]);
      *(uint4*)(dst + ((size_t)tap * 256 + oc) * IC + ic0 + ch * 8) = pk.u;
    }
  } else if (abid < 3136) {
    // ---- h1p border zero (interior overwritten by conv1) ----
    const int s = (abid - 2048) * 256 + threadIdx.x;
    const int px = s >> 5, ch8 = s & 31;
    const int b = px / 1088, r = px % 1088;
    int y, x;
    if (r < 704) { const int yi = r / 88; y = (yi < 4) ? yi : 48 + yi; x = r % 88; }
    else { const int r2 = r - 704; y = 4 + (r2 >> 3); const int xi = r2 & 7; x = (xi < 4) ? xi : 80 + xi; }
    *(uint4*)(h1p + ((size_t)(b * 56 + y) * 88 + x) * 256 + ch8 * 8) = z4;
  } else {
    // ---- BN folding: A = g/sqrt(v+eps), Bc = (conv_bias - m)*A + b ----
    const int i = threadIdx.x;
    float a1 = g1[i] / sqrtf(v1[i] + 1e-5f);
    cst[i]       = a1;
    cst[256 + i] = (ob1[i] - m1[i]) * a1 + b1[i];
    float a2 = g2[i] / sqrtf(v2[i] + 1e-5f);
    cst[512 + i] = a2;
    cst[768 + i] = (ob2[i] - m2[i]) * a2 + b2[i];
  }
}

// ---------------- MFMA implicit-GEMM conv (PROVEN — do not touch) --------
template <int CIN, int HP, int WP, int DIL, int MODE>
__global__ __launch_bounds__(256) void conv_mfma_kernel(
    const __hip_bfloat16* __restrict__ inp, const __hip_bfloat16* __restrict__ wt,
    const float* __restrict__ bnA, const float* __restrict__ bnB,
    __hip_bfloat16* __restrict__ outp, float* __restrict__ gpool)
{
  __shared__ unsigned short As[8192] __attribute__((aligned(16)));
  __shared__ unsigned short Bs[8192] __attribute__((aligned(16)));

  // XCD swizzle (grid=480=8*60, bijective): each XCD owns one batch image.
  int bid = blockIdx.x;
  bid = (bid & 7) * 60 + (bid >> 3);
  const int ocb = bid & 1; bid >>= 1;
  const int xb = bid % 5; bid /= 5;
  const int yb = bid % 6; bid /= 6;
  const int b = bid;
  const int y0 = yb * 8, x0 = xb * 16, oc0 = ocb * 128;

  const int t = threadIdx.x;
  const int w = t >> 6, l = t & 63;
  const int col16 = l & 15, quad = l >> 4;
  const int wm = w >> 1, wn = w & 1;
  const int rsub = l >> 3;          // row within an 8-row staging chunk
  const int jj = (l & 7) ^ rsub;    // swizzled source 16B-chunk

  f32x4 acc[4][4];
  const f32x4 zf = {0.f, 0.f, 0.f, 0.f};
#pragma unroll
  for (int i = 0; i < 4; i++)
#pragma unroll
    for (int j = 0; j < 4; j++) acc[i][j] = zf;

  for (int c0 = 0; c0 < CIN; c0 += 64) {
    for (int tap = 0; tap < 9; tap++) {
      const int ty = tap / 3, tx = tap - ty * 3;
      const __hip_bfloat16* inBase =
          inp + ((size_t)(b * HP + y0 + DIL * ty) * WP + (x0 + DIL * tx)) * CIN + jj * 8 + c0;
      const __hip_bfloat16* wBase = wt + (size_t)(tap * 256 + oc0) * CIN + jj * 8 + c0;
      __syncthreads();
#pragma unroll
      for (int i = 0; i < 4; i++) {            // A: 128 pixels x 64 ch
        const int q = i * 4 + w;
        const int m = q * 8 + rsub;
        const int ry = m >> 4, rx = m & 15;
        const __hip_bfloat16* gp = inBase + (ry * WP + rx) * CIN;
        __builtin_amdgcn_global_load_lds((as1_void*)gp,
            (as3_void*)((char*)As + q * 1024), 16, 0, 0);
      }
#pragma unroll
      for (int i = 0; i < 4; i++) {            // B: 128 oc x 64 ch
        const int q = i * 4 + w;
        const int n = q * 8 + rsub;
        const __hip_bfloat16* gp = wBase + n * CIN;
        __builtin_amdgcn_global_load_lds((as1_void*)gp,
            (as3_void*)((char*)Bs + q * 1024), 16, 0, 0);
      }
      __syncthreads();
#pragma unroll
      for (int kiter = 0; kiter < 2; kiter++) {
        bf16x8 af[4], bg[4];
#pragma unroll
        for (int fi = 0; fi < 4; fi++) {       // A frag: m = lane&15
          const int m = wm * 64 + fi * 16 + col16;
          const int jc = (kiter * 4 + quad) ^ (m & 7);
          af[fi] = *(const bf16x8*)((const char*)As + m * 128 + jc * 16);
        }
#pragma unroll
        for (int fi = 0; fi < 4; fi++) {       // B frag: n = lane&15
          const int n = wn * 64 + fi * 16 + col16;
          const int jc = (kiter * 4 + quad) ^ (n & 7);
          bg[fi] = *(const bf16x8*)((const char*)Bs + n * 128 + jc * 16);
        }
#pragma unroll
        for (int fm_ = 0; fm_ < 4; fm_++)
#pragma unroll
          for (int fn_ = 0; fn_ < 4; fn_++)
            acc[fm_][fn_] = __builtin_amdgcn_mfma_f32_16x16x32_bf16(
                af[fm_], bg[fn_], acc[fm_][fn_], 0, 0, 0);
      }
    }
  }

  if (MODE == 0) {
    // C/D layout: col = lane&15 (= oc), row = quad*4 + r (= pixel)  [m89/m91]
#pragma unroll
    for (int fn_ = 0; fn_ < 4; fn_++) {
      const int oc = oc0 + wn * 64 + fn_ * 16 + col16;
      const float sa = bnA[oc], sb = bnB[oc];
#pragma unroll
      for (int fm_ = 0; fm_ < 4; fm_++) {
#pragma unroll
        for (int r = 0; r < 4; r++) {
          const int m = wm * 64 + fm_ * 16 + quad * 4 + r;
          const int y = y0 + (m >> 4), x = x0 + (m & 15);
          const float v = fmaxf(acc[fm_][fn_][r] * sa + sb, 0.f);
          outp[((size_t)(b * 56 + y + 4) * 88 + (x + 4)) * 256 + oc] = __float2bfloat16(v);
        }
      }
    }
  } else {
#pragma unroll
    for (int fn_ = 0; fn_ < 4; fn_++) {
      const int oc = oc0 + wn * 64 + fn_ * 16 + col16;
      const float sa = bnA[oc], sb = bnB[oc];
      float cs = 0.f;
#pragma unroll
      for (int fm_ = 0; fm_ < 4; fm_++)
#pragma unroll
        for (int r = 0; r < 4; r++)
          cs += fmaxf(acc[fm_][fn_][r] * sa + sb, 0.f);
      cs += __shfl_xor(cs, 16);   // combine the 4 quads holding this column
      cs += __shfl_xor(cs, 32);
      if (quad == 0) atomicAdd(&gpool[b * 256 + oc], cs);
    }
  }
}

// ---------------- FC chain (fp32) ----------------

// R10c: fc1 with inline G. Each block computes G[b][oc] = g_b[oc] +
// sum_c gpool[b][c]/3840 * g_w[oc][c] itself (2048 MAC/thread, gw L2-hot),
// then out1[j][i] = silu(fc_in[i].fc1_w[j]+b[j]); fc_in = [G[i/2] | gap[i]].
__global__ __launch_bounds__(256) void fc1_kernel(
    const float* __restrict__ gpool, const float* __restrict__ gw,
    const float* __restrict__ gb, const float* __restrict__ gapv,
    const float* __restrict__ w, const float* __restrict__ bias,
    float* __restrict__ out1)
{
  __shared__ float pool[8][256];
  __shared__ float Gl[8][256];
  __shared__ float fin[16][513];
  for (int idx = threadIdx.x; idx < 2048; idx += 256)
    pool[idx >> 8][idx & 255] = gpool[idx] * (1.f / 3840.f);
  __syncthreads();
  {
    const int oc = threadIdx.x;
    float s0, s1, s2, s3, s4, s5, s6, s7;
    const float g0 = gb[oc];
    s0 = s1 = s2 = s3 = s4 = s5 = s6 = s7 = g0;
    const float* wr = gw + oc * 256;
    for (int c = 0; c < 256; c++) {
      const float wv = wr[c];
      s0 += pool[0][c] * wv; s1 += pool[1][c] * wv;
      s2 += pool[2][c] * wv; s3 += pool[3][c] * wv;
      s4 += pool[4][c] * wv; s5 += pool[5][c] * wv;
      s6 += pool[6][c] * wv; s7 += pool[7][c] * wv;
    }
    Gl[0][oc] = s0; Gl[1][oc] = s1; Gl[2][oc] = s2; Gl[3][oc] = s3;
    Gl[4][oc] = s4; Gl[5][oc] = s5; Gl[6][oc] = s6; Gl[7][oc] = s7;
  }
  __syncthreads();
  for (int idx = threadIdx.x; idx < 16 * 512; idx += 256) {
    int i = idx >> 9, k = idx & 511;
    fin[i][k] = (k < 256) ? Gl[i >> 1][k]
                          : gapv[i * 256 + (k - 256)] * (1.f / 3840.f);
  }
  __syncthreads();
  int g = blockIdx.x * 256 + threadIdx.x;
  int j = g >> 4, i = g & 15;
  float s = bias[j];
  const float* wr = w + j * 512;
  for (int k = 0; k < 512; k++) s += fin[i][k] * wr[k];
  out1[j * 16 + i] = s / (1.f + expf(-s));
}

// wdw[i][j] = out1[i] . fc2_w[j] + b[j]   (j in 0..2303)
__global__ __launch_bounds__(256) void fc2_kernel(
    const float* __restrict__ out1, const float* __restrict__ w,
    const float* __restrict__ bias, float* __restrict__ wdw)
{
  __shared__ float fin[16][513];
  for (int idx = threadIdx.x; idx < 16 * 512; idx += 256) {
    int i = idx >> 9, k = idx & 511;
    fin[i][k] = out1[k * 16 + i];
  }
  __syncthreads();
  int g = blockIdx.x * 256 + threadIdx.x;
  int j = g >> 4, i = g & 15;
  float s = bias[j];
  const float* wr = w + j * 512;
  for (int k = 0; k < 512; k++) s += fin[i][k] * wr[k];
  wdw[i * 2304 + j] = s;
}

// per-(i,c) 3x3 depthwise, pad 1: fm = dwconv(Fs, wdw)
// R6b: plane staged in zero-padded LDS [50][82] via float4 loads; compute
// 4 px/thread from LDS; float4 stores.
__global__ __launch_bounds__(256) void dw_kernel(
    const float* __restrict__ f0, const float* __restrict__ f1,
    const float* __restrict__ wdw, float* __restrict__ fm)
{
  int i = blockIdx.x >> 8, c = blockIdx.x & 255;
  const float* src = (i < 8) ? (f0 + ((size_t)i * 256 + c) * 3840)
                             : (f1 + ((size_t)(i - 8) * 256 + c) * 3840);
  float* dst = fm + ((size_t)i * 256 + c) * 3840;
  __shared__ float w9s[9];
  __shared__ float tile[50][82];
  for (int k = threadIdx.x; k < 4100; k += 256) ((float*)tile)[k] = 0.f;
  if (threadIdx.x < 9) w9s[threadIdx.x] = wdw[i * 2304 + c * 9 + threadIdx.x];
  __syncthreads();
  for (int k = threadIdx.x; k < 960; k += 256) {
    const float4 v = *(const float4*)(src + k * 4);
    const int y = k / 20, xx = (k % 20) * 4;
    float* tp = &tile[y + 1][xx + 1];
    tp[0] = v.x; tp[1] = v.y; tp[2] = v.z; tp[3] = v.w;
  }
  __syncthreads();
  for (int k = threadIdx.x; k < 960; k += 256) {
    const int y = k / 20, xx = (k % 20) * 4;
    float r0 = 0.f, r1 = 0.f, r2 = 0.f, r3 = 0.f;
#pragma unroll
    for (int dy = 0; dy < 3; dy++) {
      const float* row = &tile[y + dy][xx];
      const float w0 = w9s[dy * 3], w1 = w9s[dy * 3 + 1], w2 = w9s[dy * 3 + 2];
      r0 += w0 * row[0] + w1 * row[1] + w2 * row[2];
      r1 += w0 * row[1] + w1 * row[2] + w2 * row[3];
      r2 += w0 * row[2] + w1 * row[3] + w2 * row[4];
      r3 += w0 * row[3] + w1 * row[4] + w2 * row[5];
    }
    float4 o; o.x = r0; o.y = r1; o.z = r2; o.w = r3;
    *(float4*)(dst + k * 4) = o;
  }
}

// R10a: fused alpha + final, register-resident, FLOAT4 loads.
// 640 threads = (x4 in 0..19) x (g in 0..31 slices of 8 channels). Each
// thread loads 3x8 float4 (4 consecutive x) ONCE, reduces per-x4 partials,
// LDS-reduces over the 32 g-slices (4 planes sequentially, reusing one
// [32][21] float4 buffer), then blends from registers. Same bytes as R5a,
// 4x fewer load instructions.
__global__ __launch_bounds__(640) void alpha_final_kernel(
    const float* __restrict__ fm, const float* __restrict__ f2,
    const float* __restrict__ apw, const float* __restrict__ apb,
    const float* __restrict__ aw, const float* __restrict__ ab,
    float* __restrict__ out)
{
  const int b = blockIdx.x / 48, y = blockIdx.x % 48;
  const int x4 = threadIdx.x % 20, g = threadIdx.x / 20;
  const size_t base = (size_t)(b * 256 + g * 8) * 3840 + y * 80 + x4 * 4;
  const float* ftm  = fm + base;
  const float* ft1m = fm + (size_t)2048 * 3840 + base;   // (b+8)*256 ch offset
  const float* ptm2 = f2 + base;

  float4 v0[8], v1[8], v2[8];
  float4 S  = {0.f, 0.f, 0.f, 0.f}, T0 = {0.f, 0.f, 0.f, 0.f};
  float4 T1 = {0.f, 0.f, 0.f, 0.f}, T2 = {0.f, 0.f, 0.f, 0.f};
#pragma unroll
  for (int cc = 0; cc < 8; cc++) {
    v0[cc] = *(const float4*)(ftm  + (size_t)cc * 3840);
    v1[cc] = *(const float4*)(ft1m + (size_t)cc * 3840);
    v2[cc] = *(const float4*)(ptm2 + (size_t)cc * 3840);
    const int c = g * 8 + cc;
    const float wa1 = apw[c], wa2 = apw[256 + c];
    const float wb0 = aw[c],  wb1 = aw[256 + c];
    f4acc(S, wa1, v1[cc]);  f4acc(S, wa2, v2[cc]);
    f4acc(T0, wb0, v0[cc]);
    f4acc(T1, wb1, v1[cc]);
    f4acc(T2, wb1, v2[cc]);
  }

  __shared__ float4 red[32][21];
  __shared__ float4 apl4[20], all4[20];
  float4 St, T0t, T1t, T2t;

  // 4 sequential plane reductions, reusing one buffer
  red[g][x4] = S;  __syncthreads();
  if (threadIdx.x < 20) {
    float4 a = red[0][threadIdx.x];
    for (int k = 1; k < 32; k++) { const float4 r = red[k][threadIdx.x];
      a.x += r.x; a.y += r.y; a.z += r.z; a.w += r.w; }
    St = a;
  }
  __syncthreads();
  red[g][x4] = T0; __syncthreads();
  if (threadIdx.x < 20) {
    float4 a = red[0][threadIdx.x];
    for (int k = 1; k < 32; k++) { const float4 r = red[k][threadIdx.x];
      a.x += r.x; a.y += r.y; a.z += r.z; a.w += r.w; }
    T0t = a;
  }
  __syncthreads();
  red[g][x4] = T1; __syncthreads();
  if (threadIdx.x < 20) {
    float4 a = red[0][threadIdx.x];
    for (int k = 1; k < 32; k++) { const float4 r = red[k][threadIdx.x];
      a.x += r.x; a.y += r.y; a.z += r.z; a.w += r.w; }
    T1t = a;
  }
  __syncthreads();
  red[g][x4] = T2; __syncthreads();
  if (threadIdx.x < 20) {
    float4 a = red[0][threadIdx.x];
    for (int k = 1; k < 32; k++) { const float4 r = red[k][threadIdx.x];
      a.x += r.x; a.y += r.y; a.z += r.z; a.w += r.w; }
    T2t = a;

    const float apb0 = apb[0], ab0 = ab[0];
    float4 ap, al;
    ap.x = 0.3f + 0.4f / (1.f + expf(-(St.x + apb0)));
    ap.y = 0.3f + 0.4f / (1.f + expf(-(St.y + apb0)));
    ap.z = 0.3f + 0.4f / (1.f + expf(-(St.z + apb0)));
    ap.w = 0.3f + 0.4f / (1.f + expf(-(St.w + apb0)));
    const float Ax = T0t.x + ap.x * T1t.x + (1.f - ap.x) * T2t.x + ab0;
    const float Ay = T0t.y + ap.y * T1t.y + (1.f - ap.y) * T2t.y + ab0;
    const float Az = T0t.z + ap.z * T1t.z + (1.f - ap.z) * T2t.z + ab0;
    const float Aw = T0t.w + ap.w * T1t.w + (1.f - ap.w) * T2t.w + ab0;
    al.x = 0.6f + 0.3f / (1.f + expf(-Ax));
    al.y = 0.6f + 0.3f / (1.f + expf(-Ay));
    al.z = 0.6f + 0.3f / (1.f + expf(-Az));
    al.w = 0.6f + 0.3f / (1.f + expf(-Aw));
    apl4[threadIdx.x] = ap; all4[threadIdx.x] = al;
  }
  __syncthreads();

  const float4 ap = apl4[x4], al = all4[x4];
  float* ob = out + base;
#pragma unroll
  for (int cc = 0; cc < 8; cc++) {
    float4 r;
    r.x = blend1(al.x, ap.x, v0[cc].x, v1[cc].x, v2[cc].x);
    r.y = blend1(al.y, ap.y, v0[cc].y, v1[cc].y, v2[cc].y);
    r.z = blend1(al.z, ap.z, v0[cc].z, v1[cc].z, v2[cc].z);
    r.w = blend1(al.w, ap.w, v0[cc].w, v1[cc].w, v2[cc].w);
    *(float4*)(ob + (size_t)cc * 3840) = r;
  }
}

// ---------------- launcher ----------------

extern "C" void kernel_launch(void* const* d_in, const int* in_sizes, int n_in,
                              void* d_out, int out_size, void* d_ws, size_t ws_size,
                              hipStream_t stream)
{
  const float* f_tm2 = (const float*)d_in[0];
  const float* f_tm1 = (const float*)d_in[1];
  const float* f_t   = (const float*)d_in[2];
  const float* ov_w1 = (const float*)d_in[3];
  const float* ov_b1 = (const float*)d_in[4];
  const float* bn1_g = (const float*)d_in[5];
  const float* bn1_b = (const float*)d_in[6];
  const float* bn1_m = (const float*)d_in[7];
  const float* bn1_v = (const float*)d_in[8];
  const float* ov_w2 = (const float*)d_in[9];
  const float* ov_b2 = (const float*)d_in[10];
  const float* bn2_g = (const float*)d_in[11];
  const float* bn2_b = (const float*)d_in[12];
  const float* bn2_m = (const float*)d_in[13];
  const float* bn2_v = (const float*)d_in[14];
  const float* g_w   = (const float*)d_in[15];
  const float* g_b   = (const float*)d_in[16];
  const float* fc1_w = (const float*)d_in[17];
  const float* fc1_b = (const float*)d_in[18];
  const float* fc2_w = (const float*)d_in[19];
  const float* fc2_b = (const float*)d_in[20];
  const float* ap_w  = (const float*)d_in[21];
  const float* ap_b  = (const float*)d_in[22];
  const float* a_w   = (const float*)d_in[23];
  const float* a_b   = (const float*)d_in[24];

  // workspace layout (fm aliases in1p/wt1/wt2/h1p-head: those are dead by dw)
  char* ws = (char*)d_ws;
  float* fm            = (float*)ws;                    // 62,914,560 B
  __hip_bfloat16* in1p = (__hip_bfloat16*)ws;           // 53,673,984 B (8x52x84x768)
  __hip_bfloat16* wt1  = (__hip_bfloat16*)(ws + 53673984);  //  3,538,944 B
  __hip_bfloat16* wt2  = (__hip_bfloat16*)(ws + 57212928);  //  1,179,648 B
  __hip_bfloat16* h1p  = (__hip_bfloat16*)(ws + 58392576);  // 20,185,088 B (8x56x88x256)
  float* gpool         = (float*)(ws + 78577664);       //  8 KB
  float* gapv          = (float*)(ws + 78585856);       // 16 KB (contiguous after gpool)
  float* out1          = (float*)(ws + 78610432);       // 32 KB
  float* wdw           = (float*)(ws + 78643200);       // 144 KB
  float* cst           = (float*)(ws + 79036416);       //  4 KB  (total ~75.4 MiB)

  // zero gpool+gapv BEFORE prep (pad's gapv atomics must see zeros)
  hipMemsetAsync(gpool, 0, 24576, stream);

  prep_kernel<<<5441, 256, 0, stream>>>(f_tm2, f_tm1, f_t, in1p, gapv,
      ov_w1, ov_w2, ov_b1, bn1_g, bn1_b, bn1_m, bn1_v,
      ov_b2, bn2_g, bn2_b, bn2_m, bn2_v, wt1, wt2, h1p, cst);

  // conv1: 768ch dil=2 -> h1p (bf16, padded +4);  conv2: 256ch dil=4 -> pooled sums
  conv_mfma_kernel<768, 52, 84, 2, 0><<<480, 256, 0, stream>>>(in1p, wt1, cst, cst + 256, h1p, nullptr);
  conv_mfma_kernel<256, 56, 88, 4, 1><<<480, 256, 0, stream>>>(h1p, wt2, cst + 512, cst + 768, nullptr, gpool);

  fc1_kernel<<<32, 256, 0, stream>>>(gpool, g_w, g_b, gapv, fc1_w, fc1_b, out1);
  fc2_kernel<<<144, 256, 0, stream>>>(out1, fc2_w, fc2_b, wdw);
  dw_kernel<<<4096, 256, 0, stream>>>(f_t, f_tm1, wdw, fm);
  alpha_final_kernel<<<384, 640, 0, stream>>>(fm, f_tm2, ap_w, ap_b, a_w, a_b, (float*)d_out);
}

// Round 11
// 447.306 us; speedup vs baseline: 1.0025x; 1.0025x over previous
//
#include <hip/hip_runtime.h>
#include <hip/hip_bf16.h>
#include <math.h>

// ---------------------------------------------------------------------------
// ContMixT: f_concat -> conv3x3(d2) BN ReLU -> conv3x3(d4) BN ReLU -> pool ->
// 1x1 -> fc -> per-(batch,channel) 3x3 depthwise -> two 1x1 gates -> blend.
// conv1/conv2: bf16 MFMA implicit GEMM (m97-style 128x128 tile, BK=64,
// global_load_lds width=16, xor-swizzled LDS) — R2 structure, PROVEN; R3/R6/R8
// falsified dbuf, in-block split-K, and cross-block split-K: ~130us/36%
// MfmaUtil is this structure's ceiling. Do not touch.
// R1: pad_concat tiled transpose. R2: c0-outer/tap-inner + XCD swizzle.
// R4/R5: alpha+final fused, register-resident; gap fused into pad_concat;
// border stores instead of memsets. R6b: dw LDS-tiled. R9: aux consolidation.
// R10: alpha float4 loads + prep merge + fcG-in-fc1 — NEUTRAL.
// R11: fm intermediate in BF16 (-63MB write, -31MB read) — FAILED: border
//      zero covered 260 cells with 256 threads; tile[45..48][81] kept garbage.
// R12: fix = strided border-zero loop (all 260 cells). Nothing else changed.
// ---------------------------------------------------------------------------

typedef __bf16 bf16x8 __attribute__((ext_vector_type(8)));
typedef float f32x4 __attribute__((ext_vector_type(4)));
typedef __attribute__((address_space(1))) void as1_void;
typedef __attribute__((address_space(3))) void as3_void;

__device__ __forceinline__ void f4acc(float4& a, float s, const float4& v) {
  a.x += s * v.x; a.y += s * v.y; a.z += s * v.z; a.w += s * v.w;
}
__device__ __forceinline__ float blend1(float al, float ap, float a, float b, float c) {
  return al * a + (1.f - al) * (ap * b + (1.f - ap) * c);
}
__device__ __forceinline__ float b2f(unsigned short u) {
  union { unsigned int i; float f; } x; x.i = ((unsigned int)u) << 16; return x.f;
}

// ---------------- prep: pad_concat + repack + borders + BN fold ----------
// grid 5441: [0,2304) pad_concat; [2304,4352) weight repack;
// [4352,5440) h1p border zero; [5440] BN fold.
__global__ __launch_bounds__(256) void prep_kernel(
    const float* __restrict__ f2, const float* __restrict__ f1, const float* __restrict__ f0,
    __hip_bfloat16* __restrict__ out, float* __restrict__ gapv,
    const float* __restrict__ w1, const float* __restrict__ w2,
    const float* __restrict__ ob1, const float* __restrict__ g1, const float* __restrict__ b1,
    const float* __restrict__ m1, const float* __restrict__ v1,
    const float* __restrict__ ob2, const float* __restrict__ g2, const float* __restrict__ b2,
    const float* __restrict__ m2, const float* __restrict__ v2,
    __hip_bfloat16* __restrict__ wt1, __hip_bfloat16* __restrict__ wt2,
    __hip_bfloat16* __restrict__ h1p, float* __restrict__ cst)
{
  __shared__ float shbuf[128 * 85];
  const uint4 z4 = {0u, 0u, 0u, 0u};

  if (blockIdx.x < 2304) {
    // ---- pad_concat: NCHW fp32 x3 -> padded NHWC bf16, + gap row-sums ----
    int bid = blockIdx.x;
    const int cg = bid % 6; bid /= 6;
    const int y = bid % 48;
    const int b = bid / 48;
    const float* src = (cg < 2) ? f2 : ((cg < 4) ? f1 : f0);
    const int ccbase = (cg & 1) * 128;

    // phase 1: 128 c x 20 x4 = 2560 float4 loads, 10 per thread
#pragma unroll
    for (int it = 0; it < 10; it++) {
      const int idx = it * 256 + threadIdx.x;
      const int cl = idx / 20, x4 = idx % 20;
      const float4 v = *(const float4*)(src +
          (((size_t)b * 256 + ccbase + cl) * 48 + y) * 80 + x4 * 4);
      float* t = shbuf + cl * 85 + x4 * 4;
      t[0] = v.x; t[1] = v.y; t[2] = v.z; t[3] = v.w;
    }

    // x-borders of this padded row (x = 0,1,82,83), 128 ch = 32 uint4
    if (threadIdx.x < 32) {
      const int xb_ = threadIdx.x >> 3, ch8 = threadIdx.x & 7;
      const int xx = (xb_ < 2) ? xb_ : (80 + xb_);
      *(uint4*)(out + ((size_t)(b * 52 + y + 2) * 84 + xx) * 768 + cg * 128 + ch8 * 8) = z4;
    }
    // y-border rows (0,1 by y==0 blocks; 50,51 by y==47 blocks)
    if (y == 0 || y == 47) {
      const int r0 = (y == 0) ? 0 : 50;
      for (int idx = threadIdx.x; idx < 1344; idx += 256) {
        const int rr = idx / 672, rem = idx % 672;
        const int xx = rem >> 3, ch8 = rem & 7;
        *(uint4*)(out + ((size_t)(b * 52 + r0 + rr) * 84 + xx) * 768 + cg * 128 + ch8 * 8) = z4;
      }
    }
    __syncthreads();

    // phase 2: 80 x x 16 chunks = 1280 16B stores, 5 per thread
    __hip_bfloat16* obase = out + ((size_t)(b * 52 + y + 2) * 84 + 2) * 768 + cg * 128;
#pragma unroll
    for (int it = 0; it < 5; it++) {
      const int idx = it * 256 + threadIdx.x;
      const int chunk = idx & 15, x = idx >> 4;
      const float* t = shbuf + chunk * 8 * 85 + x;
      union { __hip_bfloat16 h[8]; uint4 u; } pk;
#pragma unroll
      for (int j = 0; j < 8; j++) pk.h[j] = __float2bfloat16(t[j * 85]);
      *(uint4*)(obase + (size_t)x * 768 + chunk * 8) = pk.u;
    }

    // gap row-sums for f_t (cg 4,5 -> i=b) and f_tm1 (cg 2,3 -> i=b+8)
    if (cg >= 2) {
      const int i_gap = (cg >= 4) ? b : (b + 8);
      const int cl = threadIdx.x >> 1, half = threadIdx.x & 1;
      const float* t = shbuf + cl * 85 + half * 40;
      float s = 0.f;
#pragma unroll
      for (int k = 0; k < 40; k++) s += t[k];
      s += __shfl_xor(s, 1);
      if (half == 0) atomicAdd(&gapv[i_gap * 256 + ccbase + cl], s);
    }
    return;
  }

  const int abid = blockIdx.x - 2304;
  if (abid < 2048) {
    // ---- coalesced weight repack: OIHW fp32 -> [tap][oc][ic] bf16 ----
    const float* w = (abid < 1536) ? w1 : w2;
    __hip_bfloat16* dst = (abid < 1536) ? wt1 : wt2;
    const int IC = (abid < 1536) ? 768 : 256;
    const int lb = (abid < 1536) ? abid : (abid - 1536);
    const int nicb = IC >> 7;
    const int icb = lb % nicb, oc = lb / nicb;
    const int ic0 = icb * 128;
    const float* src = w + ((size_t)oc * IC + ic0) * 9;
    for (int k = threadIdx.x; k < 1152; k += 256) shbuf[k] = src[k];
    __syncthreads();
    if (threadIdx.x < 144) {
      const int tap = threadIdx.x / 16, ch = threadIdx.x % 16;
      union { __hip_bfloat16 h[8]; uint4 u; } pk;
#pragma unroll
      for (int j = 0; j < 8; j++) pk.h[j] = __float2bfloat16(shbuf[(ch * 8 + j) * 9 + tap]);
      *(uint4*)(dst + ((size_t)tap * 256 + oc) * IC + ic0 + ch * 8) = pk.u;
    }
  } else if (abid < 3136) {
    // ---- h1p border zero (interior overwritten by conv1) ----
    const int s = (abid - 2048) * 256 + threadIdx.x;
    const int px = s >> 5, ch8 = s & 31;
    const int b = px / 1088, r = px % 1088;
    int y, x;
    if (r < 704) { const int yi = r / 88; y = (yi < 4) ? yi : 48 + yi; x = r % 88; }
    else { const int r2 = r - 704; y = 4 + (r2 >> 3); const int xi = r2 & 7; x = (xi < 4) ? xi : 80 + xi; }
    *(uint4*)(h1p + ((size_t)(b * 56 + y) * 88 + x) * 256 + ch8 * 8) = z4;
  } else {
    // ---- BN folding: A = g/sqrt(v+eps), Bc = (conv_bias - m)*A + b ----
    const int i = threadIdx.x;
    float a1 = g1[i] / sqrtf(v1[i] + 1e-5f);
    cst[i]       = a1;
    cst[256 + i] = (ob1[i] - m1[i]) * a1 + b1[i];
    float a2 = g2[i] / sqrtf(v2[i] + 1e-5f);
    cst[512 + i] = a2;
    cst[768 + i] = (ob2[i] - m2[i]) * a2 + b2[i];
  }
}

// ---------------- MFMA implicit-GEMM conv (PROVEN — do not touch) --------
template <int CIN, int HP, int WP, int DIL, int MODE>
__global__ __launch_bounds__(256) void conv_mfma_kernel(
    const __hip_bfloat16* __restrict__ inp, const __hip_bfloat16* __restrict__ wt,
    const float* __restrict__ bnA, const float* __restrict__ bnB,
    __hip_bfloat16* __restrict__ outp, float* __restrict__ gpool)
{
  __shared__ unsigned short As[8192] __attribute__((aligned(16)));
  __shared__ unsigned short Bs[8192] __attribute__((aligned(16)));

  // XCD swizzle (grid=480=8*60, bijective): each XCD owns one batch image.
  int bid = blockIdx.x;
  bid = (bid & 7) * 60 + (bid >> 3);
  const int ocb = bid & 1; bid >>= 1;
  const int xb = bid % 5; bid /= 5;
  const int yb = bid % 6; bid /= 6;
  const int b = bid;
  const int y0 = yb * 8, x0 = xb * 16, oc0 = ocb * 128;

  const int t = threadIdx.x;
  const int w = t >> 6, l = t & 63;
  const int col16 = l & 15, quad = l >> 4;
  const int wm = w >> 1, wn = w & 1;
  const int rsub = l >> 3;          // row within an 8-row staging chunk
  const int jj = (l & 7) ^ rsub;    // swizzled source 16B-chunk

  f32x4 acc[4][4];
  const f32x4 zf = {0.f, 0.f, 0.f, 0.f};
#pragma unroll
  for (int i = 0; i < 4; i++)
#pragma unroll
    for (int j = 0; j < 4; j++) acc[i][j] = zf;

  for (int c0 = 0; c0 < CIN; c0 += 64) {
    for (int tap = 0; tap < 9; tap++) {
      const int ty = tap / 3, tx = tap - ty * 3;
      const __hip_bfloat16* inBase =
          inp + ((size_t)(b * HP + y0 + DIL * ty) * WP + (x0 + DIL * tx)) * CIN + jj * 8 + c0;
      const __hip_bfloat16* wBase = wt + (size_t)(tap * 256 + oc0) * CIN + jj * 8 + c0;
      __syncthreads();
#pragma unroll
      for (int i = 0; i < 4; i++) {            // A: 128 pixels x 64 ch
        const int q = i * 4 + w;
        const int m = q * 8 + rsub;
        const int ry = m >> 4, rx = m & 15;
        const __hip_bfloat16* gp = inBase + (ry * WP + rx) * CIN;
        __builtin_amdgcn_global_load_lds((as1_void*)gp,
            (as3_void*)((char*)As + q * 1024), 16, 0, 0);
      }
#pragma unroll
      for (int i = 0; i < 4; i++) {            // B: 128 oc x 64 ch
        const int q = i * 4 + w;
        const int n = q * 8 + rsub;
        const __hip_bfloat16* gp = wBase + n * CIN;
        __builtin_amdgcn_global_load_lds((as1_void*)gp,
            (as3_void*)((char*)Bs + q * 1024), 16, 0, 0);
      }
      __syncthreads();
#pragma unroll
      for (int kiter = 0; kiter < 2; kiter++) {
        bf16x8 af[4], bg[4];
#pragma unroll
        for (int fi = 0; fi < 4; fi++) {       // A frag: m = lane&15
          const int m = wm * 64 + fi * 16 + col16;
          const int jc = (kiter * 4 + quad) ^ (m & 7);
          af[fi] = *(const bf16x8*)((const char*)As + m * 128 + jc * 16);
        }
#pragma unroll
        for (int fi = 0; fi < 4; fi++) {       // B frag: n = lane&15
          const int n = wn * 64 + fi * 16 + col16;
          const int jc = (kiter * 4 + quad) ^ (n & 7);
          bg[fi] = *(const bf16x8*)((const char*)Bs + n * 128 + jc * 16);
        }
#pragma unroll
        for (int fm_ = 0; fm_ < 4; fm_++)
#pragma unroll
          for (int fn_ = 0; fn_ < 4; fn_++)
            acc[fm_][fn_] = __builtin_amdgcn_mfma_f32_16x16x32_bf16(
                af[fm_], bg[fn_], acc[fm_][fn_], 0, 0, 0);
      }
    }
  }

  if (MODE == 0) {
    // C/D layout: col = lane&15 (= oc), row = quad*4 + r (= pixel)  [m89/m91]
#pragma unroll
    for (int fn_ = 0; fn_ < 4; fn_++) {
      const int oc = oc0 + wn * 64 + fn_ * 16 + col16;
      const float sa = bnA[oc], sb = bnB[oc];
#pragma unroll
      for (int fm_ = 0; fm_ < 4; fm_++) {
#pragma unroll
        for (int r = 0; r < 4; r++) {
          const int m = wm * 64 + fm_ * 16 + quad * 4 + r;
          const int y = y0 + (m >> 4), x = x0 + (m & 15);
          const float v = fmaxf(acc[fm_][fn_][r] * sa + sb, 0.f);
          outp[((size_t)(b * 56 + y + 4) * 88 + (x + 4)) * 256 + oc] = __float2bfloat16(v);
        }
      }
    }
  } else {
#pragma unroll
    for (int fn_ = 0; fn_ < 4; fn_++) {
      const int oc = oc0 + wn * 64 + fn_ * 16 + col16;
      const float sa = bnA[oc], sb = bnB[oc];
      float cs = 0.f;
#pragma unroll
      for (int fm_ = 0; fm_ < 4; fm_++)
#pragma unroll
        for (int r = 0; r < 4; r++)
          cs += fmaxf(acc[fm_][fn_][r] * sa + sb, 0.f);
      cs += __shfl_xor(cs, 16);   // combine the 4 quads holding this column
      cs += __shfl_xor(cs, 32);
      if (quad == 0) atomicAdd(&gpool[b * 256 + oc], cs);
    }
  }
}

// ---------------- FC chain (fp32) ----------------

// R10c: fc1 with inline G. Each block computes G[b][oc] = g_b[oc] +
// sum_c gpool[b][c]/3840 * g_w[oc][c] itself (gw L2-hot), then
// out1[j][i] = silu(fc_in[i].fc1_w[j]+b[j]); fc_in = [G[i/2] | gap[i]].
__global__ __launch_bounds__(256) void fc1_kernel(
    const float* __restrict__ gpool, const float* __restrict__ gw,
    const float* __restrict__ gb, const float* __restrict__ gapv,
    const float* __restrict__ w, const float* __restrict__ bias,
    float* __restrict__ out1)
{
  __shared__ float pool[8][256];
  __shared__ float Gl[8][256];
  __shared__ float fin[16][513];
  for (int idx = threadIdx.x; idx < 2048; idx += 256)
    pool[idx >> 8][idx & 255] = gpool[idx] * (1.f / 3840.f);
  __syncthreads();
  {
    const int oc = threadIdx.x;
    float s0, s1, s2, s3, s4, s5, s6, s7;
    const float g0 = gb[oc];
    s0 = s1 = s2 = s3 = s4 = s5 = s6 = s7 = g0;
    const float* wr = gw + oc * 256;
    for (int c = 0; c < 256; c++) {
      const float wv = wr[c];
      s0 += pool[0][c] * wv; s1 += pool[1][c] * wv;
      s2 += pool[2][c] * wv; s3 += pool[3][c] * wv;
      s4 += pool[4][c] * wv; s5 += pool[5][c] * wv;
      s6 += pool[6][c] * wv; s7 += pool[7][c] * wv;
    }
    Gl[0][oc] = s0; Gl[1][oc] = s1; Gl[2][oc] = s2; Gl[3][oc] = s3;
    Gl[4][oc] = s4; Gl[5][oc] = s5; Gl[6][oc] = s6; Gl[7][oc] = s7;
  }
  __syncthreads();
  for (int idx = threadIdx.x; idx < 16 * 512; idx += 256) {
    int i = idx >> 9, k = idx & 511;
    fin[i][k] = (k < 256) ? Gl[i >> 1][k]
                          : gapv[i * 256 + (k - 256)] * (1.f / 3840.f);
  }
  __syncthreads();
  int g = blockIdx.x * 256 + threadIdx.x;
  int j = g >> 4, i = g & 15;
  float s = bias[j];
  const float* wr = w + j * 512;
  for (int k = 0; k < 512; k++) s += fin[i][k] * wr[k];
  out1[j * 16 + i] = s / (1.f + expf(-s));
}

// wdw[i][j] = out1[i] . fc2_w[j] + b[j]   (j in 0..2303)
__global__ __launch_bounds__(256) void fc2_kernel(
    const float* __restrict__ out1, const float* __restrict__ w,
    const float* __restrict__ bias, float* __restrict__ wdw)
{
  __shared__ float fin[16][513];
  for (int idx = threadIdx.x; idx < 16 * 512; idx += 256) {
    int i = idx >> 9, k = idx & 511;
    fin[i][k] = out1[k * 16 + i];
  }
  __syncthreads();
  int g = blockIdx.x * 256 + threadIdx.x;
  int j = g >> 4, i = g & 15;
  float s = bias[j];
  const float* wr = w + j * 512;
  for (int k = 0; k < 512; k++) s += fin[i][k] * wr[k];
  wdw[i * 2304 + j] = s;
}

// per-(i,c) 3x3 depthwise, pad 1: fm = dwconv(Fs, wdw)   [R11: bf16 output]
// R6b: plane staged in zero-padded LDS [50][82] via float4 loads; compute
// 4 px/thread from LDS. R12: border-zero is a strided loop over all 260
// border cells (R11 used `if (tid < 260)` with a 256-thread block — the last
// 4 cells, tile[45..48][81], kept garbage -> absmax 47.5).
__global__ __launch_bounds__(256) void dw_kernel(
    const float* __restrict__ f0, const float* __restrict__ f1,
    const float* __restrict__ wdw, __hip_bfloat16* __restrict__ fm)
{
  int i = blockIdx.x >> 8, c = blockIdx.x & 255;
  const float* src = (i < 8) ? (f0 + ((size_t)i * 256 + c) * 3840)
                             : (f1 + ((size_t)(i - 8) * 256 + c) * 3840);
  __hip_bfloat16* dst = fm + ((size_t)i * 256 + c) * 3840;
  __shared__ float w9s[9];
  __shared__ float tile[50][82];
  // border-only zero: row 0 (82) + row 49 (82) + cols {0,81} rows 1..48 (96)
  for (int t = threadIdx.x; t < 260; t += 256) {
    if (t < 82)       tile[0][t] = 0.f;
    else if (t < 164) tile[49][t - 82] = 0.f;
    else if (t < 212) tile[1 + (t - 164)][0] = 0.f;
    else              tile[1 + (t - 212)][81] = 0.f;
  }
  if (threadIdx.x < 9) w9s[threadIdx.x] = wdw[i * 2304 + c * 9 + threadIdx.x];
  for (int k = threadIdx.x; k < 960; k += 256) {
    const float4 v = *(const float4*)(src + k * 4);
    const int y = k / 20, xx = (k % 20) * 4;
    float* tp = &tile[y + 1][xx + 1];
    tp[0] = v.x; tp[1] = v.y; tp[2] = v.z; tp[3] = v.w;
  }
  __syncthreads();
  for (int k = threadIdx.x; k < 960; k += 256) {
    const int y = k / 20, xx = (k % 20) * 4;
    float r0 = 0.f, r1 = 0.f, r2 = 0.f, r3 = 0.f;
#pragma unroll
    for (int dy = 0; dy < 3; dy++) {
      const float* row = &tile[y + dy][xx];
      const float w0 = w9s[dy * 3], w1 = w9s[dy * 3 + 1], w2 = w9s[dy * 3 + 2];
      r0 += w0 * row[0] + w1 * row[1] + w2 * row[2];
      r1 += w0 * row[1] + w1 * row[2] + w2 * row[3];
      r2 += w0 * row[2] + w1 * row[3] + w2 * row[4];
      r3 += w0 * row[3] + w1 * row[4] + w2 * row[5];
    }
    union { __hip_bfloat16 h[4]; uint2 u; } pk;
    pk.h[0] = __float2bfloat16(r0); pk.h[1] = __float2bfloat16(r1);
    pk.h[2] = __float2bfloat16(r2); pk.h[3] = __float2bfloat16(r3);
    *(uint2*)(dst + k * 4) = pk.u;
  }
}

// R10a/R11: fused alpha + final, register-resident; fm BF16 (8B loads).
// 640 threads = (x4 in 0..19) x (g in 0..31 slices of 8 channels). Each
// thread loads 3x8 vectors (4 consecutive x) ONCE, reduces per-x4 partials,
// LDS-reduces over the 32 g-slices, then blends from registers.
__global__ __launch_bounds__(640) void alpha_final_kernel(
    const __hip_bfloat16* __restrict__ fm, const float* __restrict__ f2,
    const float* __restrict__ apw, const float* __restrict__ apb,
    const float* __restrict__ aw, const float* __restrict__ ab,
    float* __restrict__ out)
{
  const int b = blockIdx.x / 48, y = blockIdx.x % 48;
  const int x4 = threadIdx.x % 20, g = threadIdx.x / 20;
  const size_t base = (size_t)(b * 256 + g * 8) * 3840 + y * 80 + x4 * 4;
  const __hip_bfloat16* ftm  = fm + base;
  const __hip_bfloat16* ft1m = fm + (size_t)2048 * 3840 + base;  // (b+8)*256 ch
  const float* ptm2 = f2 + base;

  ushort4 v0[8], v1[8];
  float4 v2[8];
  float4 S  = {0.f, 0.f, 0.f, 0.f}, T0 = {0.f, 0.f, 0.f, 0.f};
  float4 T1 = {0.f, 0.f, 0.f, 0.f}, T2 = {0.f, 0.f, 0.f, 0.f};
#pragma unroll
  for (int cc = 0; cc < 8; cc++) {
    v0[cc] = *(const ushort4*)(ftm  + (size_t)cc * 3840);
    v1[cc] = *(const ushort4*)(ft1m + (size_t)cc * 3840);
    v2[cc] = *(const float4*)(ptm2 + (size_t)cc * 3840);
    const float4 f0v = {b2f(v0[cc].x), b2f(v0[cc].y), b2f(v0[cc].z), b2f(v0[cc].w)};
    const float4 f1v = {b2f(v1[cc].x), b2f(v1[cc].y), b2f(v1[cc].z), b2f(v1[cc].w)};
    const int c = g * 8 + cc;
    const float wa1 = apw[c], wa2 = apw[256 + c];
    const float wb0 = aw[c],  wb1 = aw[256 + c];
    f4acc(S, wa1, f1v);  f4acc(S, wa2, v2[cc]);
    f4acc(T0, wb0, f0v);
    f4acc(T1, wb1, f1v);
    f4acc(T2, wb1, v2[cc]);
  }

  __shared__ float4 red[32][21];
  __shared__ float4 apl4[20], all4[20];
  float4 St, T0t, T1t, T2t;

  // 4 sequential plane reductions, reusing one buffer
  red[g][x4] = S;  __syncthreads();
  if (threadIdx.x < 20) {
    float4 a = red[0][threadIdx.x];
    for (int k = 1; k < 32; k++) { const float4 r = red[k][threadIdx.x];
      a.x += r.x; a.y += r.y; a.z += r.z; a.w += r.w; }
    St = a;
  }
  __syncthreads();
  red[g][x4] = T0; __syncthreads();
  if (threadIdx.x < 20) {
    float4 a = red[0][threadIdx.x];
    for (int k = 1; k < 32; k++) { const float4 r = red[k][threadIdx.x];
      a.x += r.x; a.y += r.y; a.z += r.z; a.w += r.w; }
    T0t = a;
  }
  __syncthreads();
  red[g][x4] = T1; __syncthreads();
  if (threadIdx.x < 20) {
    float4 a = red[0][threadIdx.x];
    for (int k = 1; k < 32; k++) { const float4 r = red[k][threadIdx.x];
      a.x += r.x; a.y += r.y; a.z += r.z; a.w += r.w; }
    T1t = a;
  }
  __syncthreads();
  red[g][x4] = T2; __syncthreads();
  if (threadIdx.x < 20) {
    float4 a = red[0][threadIdx.x];
    for (int k = 1; k < 32; k++) { const float4 r = red[k][threadIdx.x];
      a.x += r.x; a.y += r.y; a.z += r.z; a.w += r.w; }
    T2t = a;

    const float apb0 = apb[0], ab0 = ab[0];
    float4 ap, al;
    ap.x = 0.3f + 0.4f / (1.f + expf(-(St.x + apb0)));
    ap.y = 0.3f + 0.4f / (1.f + expf(-(St.y + apb0)));
    ap.z = 0.3f + 0.4f / (1.f + expf(-(St.z + apb0)));
    ap.w = 0.3f + 0.4f / (1.f + expf(-(St.w + apb0)));
    const float Ax = T0t.x + ap.x * T1t.x + (1.f - ap.x) * T2t.x + ab0;
    const float Ay = T0t.y + ap.y * T1t.y + (1.f - ap.y) * T2t.y + ab0;
    const float Az = T0t.z + ap.z * T1t.z + (1.f - ap.z) * T2t.z + ab0;
    const float Aw = T0t.w + ap.w * T1t.w + (1.f - ap.w) * T2t.w + ab0;
    al.x = 0.6f + 0.3f / (1.f + expf(-Ax));
    al.y = 0.6f + 0.3f / (1.f + expf(-Ay));
    al.z = 0.6f + 0.3f / (1.f + expf(-Az));
    al.w = 0.6f + 0.3f / (1.f + expf(-Aw));
    apl4[threadIdx.x] = ap; all4[threadIdx.x] = al;
  }
  __syncthreads();

  const float4 ap = apl4[x4], al = all4[x4];
  float* ob = out + base;
#pragma unroll
  for (int cc = 0; cc < 8; cc++) {
    float4 r;
    r.x = blend1(al.x, ap.x, b2f(v0[cc].x), b2f(v1[cc].x), v2[cc].x);
    r.y = blend1(al.y, ap.y, b2f(v0[cc].y), b2f(v1[cc].y), v2[cc].y);
    r.z = blend1(al.z, ap.z, b2f(v0[cc].z), b2f(v1[cc].z), v2[cc].z);
    r.w = blend1(al.w, ap.w, b2f(v0[cc].w), b2f(v1[cc].w), v2[cc].w);
    *(float4*)(ob + (size_t)cc * 3840) = r;
  }
}

// ---------------- launcher ----------------

extern "C" void kernel_launch(void* const* d_in, const int* in_sizes, int n_in,
                              void* d_out, int out_size, void* d_ws, size_t ws_size,
                              hipStream_t stream)
{
  const float* f_tm2 = (const float*)d_in[0];
  const float* f_tm1 = (const float*)d_in[1];
  const float* f_t   = (const float*)d_in[2];
  const float* ov_w1 = (const float*)d_in[3];
  const float* ov_b1 = (const float*)d_in[4];
  const float* bn1_g = (const float*)d_in[5];
  const float* bn1_b = (const float*)d_in[6];
  const float* bn1_m = (const float*)d_in[7];
  const float* bn1_v = (const float*)d_in[8];
  const float* ov_w2 = (const float*)d_in[9];
  const float* ov_b2 = (const float*)d_in[10];
  const float* bn2_g = (const float*)d_in[11];
  const float* bn2_b = (const float*)d_in[12];
  const float* bn2_m = (const float*)d_in[13];
  const float* bn2_v = (const float*)d_in[14];
  const float* g_w   = (const float*)d_in[15];
  const float* g_b   = (const float*)d_in[16];
  const float* fc1_w = (const float*)d_in[17];
  const float* fc1_b = (const float*)d_in[18];
  const float* fc2_w = (const float*)d_in[19];
  const float* fc2_b = (const float*)d_in[20];
  const float* ap_w  = (const float*)d_in[21];
  const float* ap_b  = (const float*)d_in[22];
  const float* a_w   = (const float*)d_in[23];
  const float* a_b   = (const float*)d_in[24];

  // workspace layout (fm aliases in1p head: in1p is dead by dw; fm is bf16,
  // 16x256x3840x2 = 31,457,280 B)
  char* ws = (char*)d_ws;
  __hip_bfloat16* fm   = (__hip_bfloat16*)ws;           // 31,457,280 B (R11)
  __hip_bfloat16* in1p = (__hip_bfloat16*)ws;           // 53,673,984 B (8x52x84x768)
  __hip_bfloat16* wt1  = (__hip_bfloat16*)(ws + 53673984);  //  3,538,944 B
  __hip_bfloat16* wt2  = (__hip_bfloat16*)(ws + 57212928);  //  1,179,648 B
  __hip_bfloat16* h1p  = (__hip_bfloat16*)(ws + 58392576);  // 20,185,088 B (8x56x88x256)
  float* gpool         = (float*)(ws + 78577664);       //  8 KB
  float* gapv          = (float*)(ws + 78585856);       // 16 KB (contiguous after gpool)
  float* out1          = (float*)(ws + 78610432);       // 32 KB
  float* wdw           = (float*)(ws + 78643200);       // 144 KB
  float* cst           = (float*)(ws + 79036416);       //  4 KB  (total ~75.4 MiB)

  // zero gpool+gapv BEFORE prep (pad's gapv atomics must see zeros)
  hipMemsetAsync(gpool, 0, 24576, stream);

  prep_kernel<<<5441, 256, 0, stream>>>(f_tm2, f_tm1, f_t, in1p, gapv,
      ov_w1, ov_w2, ov_b1, bn1_g, bn1_b, bn1_m, bn1_v,
      ov_b2, bn2_g, bn2_b, bn2_m, bn2_v, wt1, wt2, h1p, cst);

  // conv1: 768ch dil=2 -> h1p (bf16, padded +4);  conv2: 256ch dil=4 -> pooled sums
  conv_mfma_kernel<768, 52, 84, 2, 0><<<480, 256, 0, stream>>>(in1p, wt1, cst, cst + 256, h1p, nullptr);
  conv_mfma_kernel<256, 56, 88, 4, 1><<<480, 256, 0, stream>>>(h1p, wt2, cst + 512, cst + 768, nullptr, gpool);

  fc1_kernel<<<32, 256, 0, stream>>>(gpool, g_w, g_b, gapv, fc1_w, fc1_b, out1);
  fc2_kernel<<<144, 256, 0, stream>>>(out1, fc2_w, fc2_b, wdw);
  dw_kernel<<<4096, 256, 0, stream>>>(f_t, f_tm1, wdw, fm);
  alpha_final_kernel<<<384, 640, 0, stream>>>(fm, f_tm2, ap_w, ap_b, a_w, a_b, (float*)d_out);
}